// Round 1
// baseline (420.607 us; speedup 1.0000x reference)
//
#include <hip/hip_runtime.h>
#include <math.h>

#define DIM 64
#define NE 1024
#define NROW 65536
#define BM 64
#define BN 64
#define NCHUNK (NE / BN)
#define NELEM (NROW * DIM)  // 4194304

// ws layout: [0,4096): colnorms (1024 f32). [4096,4112): two f64 accumulators.

__global__ void colnorm_kernel(const float* __restrict__ embed, float* __restrict__ cn) {
  int j = blockIdx.x * blockDim.x + threadIdx.x;
  float s = 0.f;
#pragma unroll
  for (int d = 0; d < DIM; ++d) {
    float e = embed[d * NE + j];
    s = fmaf(e, e, s);
  }
  cn[j] = s;
}

__launch_bounds__(256, 2)
__global__ void vq_kernel(const float* __restrict__ input,
                          const float* __restrict__ embed,
                          const float* __restrict__ cn,
                          float* __restrict__ out,
                          double* __restrict__ acc) {
  __shared__ float Xt[DIM][BM + 4];   // [d][r]
  __shared__ float Et[DIM][BN + 4];   // [d][j] for score GEMM
  __shared__ float Ett[BN][DIM + 4];  // [j][d] for PV GEMM
  __shared__ float Pt[BN][BM + 4];    // [j][r]
  __shared__ float redd[4], redl[4];

  const int tid = threadIdx.x;
  const int ty = tid >> 4;  // 0..15: row group (4 rows)
  const int tx = tid & 15;  // 0..15: col group (4 cols)
  const int r0 = blockIdx.x * BM;

  // stage X^T: input[(r0+r)*64 + d] -> Xt[d][r]
#pragma unroll
  for (int it = 0; it < 4; ++it) {
    int flat = it * 1024 + tid * 4;  // 0..4095
    int r = flat >> 6;
    int d = flat & 63;
    float4 v = *reinterpret_cast<const float4*>(&input[(size_t)(r0 + r) * DIM + d]);
    Xt[d + 0][r] = v.x;
    Xt[d + 1][r] = v.y;
    Xt[d + 2][r] = v.z;
    Xt[d + 3][r] = v.w;
  }

  float m[4], l[4], bv[4];
  int bi[4];
  float q[4][4];
#pragma unroll
  for (int i = 0; i < 4; ++i) {
    m[i] = -INFINITY;
    l[i] = 0.f;
    bv[i] = -INFINITY;
    bi[i] = 0;
#pragma unroll
    for (int jd = 0; jd < 4; ++jd) q[i][jd] = 0.f;
  }

  for (int c = 0; c < NCHUNK; ++c) {
    __syncthreads();  // prev GEMM2 done before overwriting Et/Ett/Pt
    // stage E chunk in both layouts
#pragma unroll
    for (int it = 0; it < 4; ++it) {
      int flat = it * 1024 + tid * 4;
      int d = flat >> 6;
      int j = flat & 63;
      float4 v = *reinterpret_cast<const float4*>(&embed[(size_t)d * NE + c * BN + j]);
      *reinterpret_cast<float4*>(&Et[d][j]) = v;
      Ett[j + 0][d] = v.x;
      Ett[j + 1][d] = v.y;
      Ett[j + 2][d] = v.z;
      Ett[j + 3][d] = v.w;
    }
    __syncthreads();

    // GEMM1: s[4][4] = X[4 rows] . E[4 cols] over d=64
    float s[4][4];
#pragma unroll
    for (int i = 0; i < 4; ++i)
#pragma unroll
      for (int jj = 0; jj < 4; ++jj) s[i][jj] = 0.f;

#pragma unroll 8
    for (int d = 0; d < DIM; ++d) {
      float4 xv = *reinterpret_cast<const float4*>(&Xt[d][ty * 4]);
      float4 ev = *reinterpret_cast<const float4*>(&Et[d][tx * 4]);
      float xr[4] = {xv.x, xv.y, xv.z, xv.w};
      float er[4] = {ev.x, ev.y, ev.z, ev.w};
#pragma unroll
      for (int i = 0; i < 4; ++i)
#pragma unroll
        for (int jj = 0; jj < 4; ++jj) s[i][jj] = fmaf(xr[i], er[jj], s[i][jj]);
    }

    float4 cnv = *reinterpret_cast<const float4*>(&cn[c * BN + tx * 4]);
    float cnr[4] = {cnv.x, cnv.y, cnv.z, cnv.w};

#pragma unroll
    for (int i = 0; i < 4; ++i) {
      float t[4];
#pragma unroll
      for (int jj = 0; jj < 4; ++jj) t[jj] = fmaf(2.f, s[i][jj], -cnr[jj]);

      float rmax = fmaxf(fmaxf(t[0], t[1]), fmaxf(t[2], t[3]));
#pragma unroll
      for (int off = 1; off <= 8; off <<= 1) rmax = fmaxf(rmax, __shfl_xor(rmax, off));
      float mn = fmaxf(m[i], rmax);
      float scale = __expf(m[i] - mn);

      float p[4];
      float csum = 0.f;
#pragma unroll
      for (int jj = 0; jj < 4; ++jj) {
        p[jj] = __expf(t[jj] - mn);
        csum += p[jj];
      }
#pragma unroll
      for (int off = 1; off <= 8; off <<= 1) csum += __shfl_xor(csum, off);
      l[i] = l[i] * scale + csum;
      m[i] = mn;
#pragma unroll
      for (int jd = 0; jd < 4; ++jd) q[i][jd] *= scale;

      // argmax tracking (first-max tie-break, matching jnp.argmax)
      float lb = t[0];
      int lj = 0;
#pragma unroll
      for (int jj = 1; jj < 4; ++jj)
        if (t[jj] > lb) { lb = t[jj]; lj = jj; }
      int lidx = c * BN + tx * 4 + lj;
#pragma unroll
      for (int off = 1; off <= 8; off <<= 1) {
        float ob = __shfl_xor(lb, off);
        int oi = __shfl_xor(lidx, off);
        if (ob > lb || (ob == lb && oi < lidx)) { lb = ob; lidx = oi; }
      }
      if (lb > bv[i] || (lb == bv[i] && lidx < bi[i])) { bv[i] = lb; bi[i] = lidx; }

      // stage P transposed
#pragma unroll
      for (int jj = 0; jj < 4; ++jj) Pt[tx * 4 + jj][ty * 4 + i] = p[jj];
    }
    __syncthreads();

    // GEMM2: q[r][d] += P[r][j] * E^T[j][d] over j=64
#pragma unroll 8
    for (int j = 0; j < BN; ++j) {
      float4 pv = *reinterpret_cast<const float4*>(&Pt[j][ty * 4]);
      float4 ev = *reinterpret_cast<const float4*>(&Ett[j][tx * 4]);
      float pr[4] = {pv.x, pv.y, pv.z, pv.w};
      float er[4] = {ev.x, ev.y, ev.z, ev.w};
#pragma unroll
      for (int i = 0; i < 4; ++i)
#pragma unroll
        for (int jd = 0; jd < 4; ++jd) q[i][jd] = fmaf(pr[i], er[jd], q[i][jd]);
    }
  }

  // epilogue
  float diff_s = 0.f, loss_s = 0.f;
#pragma unroll
  for (int i = 0; i < 4; ++i) {
    float invl = 1.f / l[i];
    int r = r0 + ty * 4 + i;
    float ov[4];
#pragma unroll
    for (int jd = 0; jd < 4; ++jd) {
      int d = tx * 4 + jd;
      float h = embed[(size_t)d * NE + bi[i]];
      float qv = q[i][jd] * invl;
      float outv = qv + (h - qv);  // straight-through combine, as the reference writes it
      ov[jd] = outv;
      float x = Xt[d][ty * 4 + i];
      float dh = h - x;
      diff_s = fmaf(dh, dh, diff_s);
      float dl = outv - x;
      loss_s = fmaf(dl, dl, loss_s);
    }
    float4 o = {ov[0], ov[1], ov[2], ov[3]};
    *reinterpret_cast<float4*>(&out[(size_t)r * DIM + tx * 4]) = o;
    if (tx == 0) out[NELEM + r] = (float)bi[i];
  }

  // block-level reduction of the two sums
#pragma unroll
  for (int off = 1; off <= 32; off <<= 1) {
    diff_s += __shfl_xor(diff_s, off);
    loss_s += __shfl_xor(loss_s, off);
  }
  int wave = tid >> 6;
  if ((tid & 63) == 0) {
    redd[wave] = diff_s;
    redl[wave] = loss_s;
  }
  __syncthreads();
  if (tid == 0) {
    float ds = redd[0] + redd[1] + redd[2] + redd[3];
    float ls = redl[0] + redl[1] + redl[2] + redl[3];
    unsafeAtomicAdd(&acc[0], (double)ds);
    unsafeAtomicAdd(&acc[1], (double)ls);
  }
}

__global__ void finalize_kernel(const double* __restrict__ acc, float* __restrict__ out) {
  if (threadIdx.x == 0) {
    out[NELEM + NROW + 0] = (float)(acc[0] / (double)NELEM);
    out[NELEM + NROW + 1] = (float)(acc[1] / (double)NELEM);
  }
}

extern "C" void kernel_launch(void* const* d_in, const int* in_sizes, int n_in,
                              void* d_out, int out_size, void* d_ws, size_t ws_size,
                              hipStream_t stream) {
  const float* input = (const float*)d_in[0];
  const float* embed = (const float*)d_in[1];
  float* out = (float*)d_out;
  float* cn = (float*)d_ws;
  double* acc = (double*)((char*)d_ws + 4096);

  hipMemsetAsync(acc, 0, 2 * sizeof(double), stream);
  colnorm_kernel<<<NE / 256, 256, 0, stream>>>(embed, cn);
  vq_kernel<<<NROW / BM, 256, 0, stream>>>(input, embed, cn, out, acc);
  finalize_kernel<<<1, 64, 0, stream>>>(acc, out);
}

// Round 3
// 220.340 us; speedup vs baseline: 1.9089x; 1.9089x over previous
//
#include <hip/hip_runtime.h>
#include <math.h>

typedef __attribute__((ext_vector_type(8))) short short8;
typedef __attribute__((ext_vector_type(4))) float f32x4;
typedef unsigned short ushort_t;
typedef unsigned int uint_t;

#define DIM 64
#define NE 1024
#define NROW 65536
#define NELEM (NROW * DIM)  // 4194304
#define MARGIN 0.1f

// ws layout (bytes):
#define OFF_BPACK 0        // 256 KB: bf16-split embed, MFMA B-frag order
#define OFF_CN 262144      // 4 KB: ||e_j||^2 fp32
#define OFF_ET 266240      // 256 KB: embed^T fp32 [code][d]
#define OFF_ACC 528384     // 8 B: f64 loss accumulator
#define OFF_FCNT 528392    // 4 B: flag count
#define OFF_FLAGS 528396   // 256 KB: flagged row ids

__device__ __forceinline__ ushort_t f2bf(float f) {
  uint_t u = __float_as_uint(f);
  uint_t r = (u + 0x7FFFu + ((u >> 16) & 1u)) >> 16;
  return (ushort_t)r;
}

// ---------------- prepack: embed -> {B-frag bf16 hi/lo, colnorms, embed^T}
__global__ void prepack_kernel(const float* __restrict__ embed, ushort_t* __restrict__ bp,
                               float* __restrict__ cn, float* __restrict__ et) {
  int code = blockIdx.x * 256 + threadIdx.x;  // 1024 threads total
  int c16 = code >> 4, cl = code & 15;
  float nrm = 0.f;
#pragma unroll 8
  for (int d = 0; d < 64; ++d) {
    float e = embed[d * NE + code];
    nrm = fmaf(e, e, nrm);
    et[code * 64 + d] = e;
    ushort_t h = f2bf(e);
    float hf = __uint_as_float((uint_t)h << 16);
    ushort_t lo = f2bf(e - hf);
    int lane = cl + ((d >> 3) & 3) * 16;
    int j = d & 7;
    int kk = d >> 5;
    bp[(((c16 * 4) + kk) * 64 + lane) * 8 + j] = h;       // hi sections 0,1
    bp[(((c16 * 4) + 2 + kk) * 64 + lane) * 8 + j] = lo;  // lo sections 2,3
  }
  cn[code] = nrm;
}

// ---------------- score: split-bf16 MFMA, per-row top-2, flag ambiguous rows
__launch_bounds__(256, 2)
__global__ void score_kernel(const float* __restrict__ input, const ushort_t* __restrict__ bp,
                             const float* __restrict__ cn, float* __restrict__ out,
                             int* __restrict__ fcnt, int* __restrict__ flags) {
  __shared__ short8 Bs[2][4][64];  // [dbuf][sec: hi_k0,hi_k1,lo_k0,lo_k1][lane]
  __shared__ float cns[NE];

  const int tid = threadIdx.x;
  const int wave = tid >> 6, lane = tid & 63;
  const int col = lane & 15, g = lane >> 4;
  const long rowbase = (long)blockIdx.x * 128 + wave * 32;  // 2 row-tiles of 16 per wave

  // stage colnorms to LDS
  *reinterpret_cast<float4*>(&cns[tid * 4]) = *reinterpret_cast<const float4*>(&cn[tid * 4]);

#define STAGE(b, c)                                                                       \
  __builtin_amdgcn_global_load_lds(                                                      \
      (const __attribute__((address_space(1))) void*)((const char*)bp + (c)*4096 + tid * 16), \
      (__attribute__((address_space(3))) void*)((char*)&Bs[b][0][0] + wave * 1024), 16, 0, 0)

  STAGE(0, 0);

  // A fragments: X rows in bf16 hi/lo, resident all-kernel
  short8 ah[2][2], al[2][2];
#pragma unroll
  for (int rt = 0; rt < 2; ++rt)
#pragma unroll
    for (int kk = 0; kk < 2; ++kk) {
      const float* xp = &input[(size_t)(rowbase + rt * 16 + col) * 64 + kk * 32 + g * 8];
      float4 x0 = *reinterpret_cast<const float4*>(xp);
      float4 x1 = *reinterpret_cast<const float4*>(xp + 4);
      float xs[8] = {x0.x, x0.y, x0.z, x0.w, x1.x, x1.y, x1.z, x1.w};
#pragma unroll
      for (int j = 0; j < 8; ++j) {
        ushort_t h = f2bf(xs[j]);
        ah[rt][kk][j] = (short)h;
        float hf = __uint_as_float((uint_t)h << 16);
        al[rt][kk][j] = (short)f2bf(xs[j] - hf);
      }
    }

  float v1[2][4], v2[2][4];
  int i1[2][4];
#pragma unroll
  for (int rt = 0; rt < 2; ++rt)
#pragma unroll
    for (int r = 0; r < 4; ++r) {
      v1[rt][r] = -INFINITY;
      v2[rt][r] = -INFINITY;
      i1[rt][r] = 0;
    }

  __syncthreads();  // chunk 0 staged (syncthreads drains vmcnt), cns ready

  for (int c = 0; c < 64; ++c) {
    const int buf = c & 1;
    if (c + 1 < 64) STAGE(buf ^ 1, c + 1);

    short8 bh0 = Bs[buf][0][lane];
    short8 bh1 = Bs[buf][1][lane];
    short8 bl0 = Bs[buf][2][lane];
    short8 bl1 = Bs[buf][3][lane];
    float cnv = cns[c * 16 + col];

    f32x4 accA = {0.f, 0.f, 0.f, 0.f};
    f32x4 accB = {0.f, 0.f, 0.f, 0.f};
    accA = __builtin_amdgcn_mfma_f32_16x16x32_bf16(ah[0][0], bh0, accA, 0, 0, 0);
    accB = __builtin_amdgcn_mfma_f32_16x16x32_bf16(ah[1][0], bh0, accB, 0, 0, 0);
    accA = __builtin_amdgcn_mfma_f32_16x16x32_bf16(ah[0][1], bh1, accA, 0, 0, 0);
    accB = __builtin_amdgcn_mfma_f32_16x16x32_bf16(ah[1][1], bh1, accB, 0, 0, 0);
    accA = __builtin_amdgcn_mfma_f32_16x16x32_bf16(al[0][0], bh0, accA, 0, 0, 0);
    accB = __builtin_amdgcn_mfma_f32_16x16x32_bf16(al[1][0], bh0, accB, 0, 0, 0);
    accA = __builtin_amdgcn_mfma_f32_16x16x32_bf16(al[0][1], bh1, accA, 0, 0, 0);
    accB = __builtin_amdgcn_mfma_f32_16x16x32_bf16(al[1][1], bh1, accB, 0, 0, 0);
    accA = __builtin_amdgcn_mfma_f32_16x16x32_bf16(ah[0][0], bl0, accA, 0, 0, 0);
    accB = __builtin_amdgcn_mfma_f32_16x16x32_bf16(ah[1][0], bl0, accB, 0, 0, 0);
    accA = __builtin_amdgcn_mfma_f32_16x16x32_bf16(ah[0][1], bl1, accA, 0, 0, 0);
    accB = __builtin_amdgcn_mfma_f32_16x16x32_bf16(ah[1][1], bl1, accB, 0, 0, 0);

    const int code = c * 16 + col;
#pragma unroll
    for (int r = 0; r < 4; ++r) {
      float v = fmaf(2.f, accA[r], -cnv);
      float nv2 = fmaxf(v2[0][r], fminf(v1[0][r], v));
      bool gt = v > v1[0][r];
      i1[0][r] = gt ? code : i1[0][r];
      v1[0][r] = gt ? v : v1[0][r];
      v2[0][r] = nv2;
    }
#pragma unroll
    for (int r = 0; r < 4; ++r) {
      float v = fmaf(2.f, accB[r], -cnv);
      float nv2 = fmaxf(v2[1][r], fminf(v1[1][r], v));
      bool gt = v > v1[1][r];
      i1[1][r] = gt ? code : i1[1][r];
      v1[1][r] = gt ? v : v1[1][r];
      v2[1][r] = nv2;
    }
    __syncthreads();  // all waves done reading buf; staged chunk c+1 complete after this
  }

  // merge top-2 across the 16 col-lanes of each row group; write idx + flags
#pragma unroll
  for (int rt = 0; rt < 2; ++rt)
#pragma unroll
    for (int r = 0; r < 4; ++r) {
      float bv1 = v1[rt][r], bv2 = v2[rt][r];
      int bidx = i1[rt][r];
#pragma unroll
      for (int off = 1; off <= 8; off <<= 1) {
        float ov1 = __shfl_xor(bv1, off);
        int oi = __shfl_xor(bidx, off);
        float ov2 = __shfl_xor(bv2, off);
        bool take = (ov1 > bv1) || (ov1 == bv1 && oi < bidx);
        float nv2 = take ? fmaxf(bv1, ov2) : fmaxf(bv2, ov1);
        bv1 = take ? ov1 : bv1;
        bidx = take ? oi : bidx;
        bv2 = nv2;
      }
      if (col == 0) {
        long row = rowbase + rt * 16 + g * 4 + r;
        out[NELEM + row] = (float)bidx;
        if (bv1 - bv2 < MARGIN) {
          int p = atomicAdd(fcnt, 1);
          flags[p] = (int)row;
        }
      }
    }
#undef STAGE
}

// ---------------- fixup: exact f64 argmax for flagged rows (8 rows / block-pass)
__global__ void fixup_kernel(const float* __restrict__ input, const float* __restrict__ embed,
                             float* __restrict__ out, const int* __restrict__ fcnt,
                             const int* __restrict__ flags) {
  __shared__ float Xs[8][64];
  __shared__ double Wv[4][8];
  __shared__ int Wi[4][8];
  const int tid = threadIdx.x;
  const int lane = tid & 63, wv = tid >> 6;
  const int count = *fcnt;

  for (int base = blockIdx.x * 8; base < count; base += 256 * 8) {
    int rows[8];
#pragma unroll
    for (int i = 0; i < 8; ++i) {
      int p = base + i;
      if (p >= count) p = count - 1;
      rows[i] = flags[p];
    }
    __syncthreads();  // previous pass finished with Xs
    if (tid < 128) {
      int r8 = tid >> 4, seg = (tid & 15) * 4;
      *reinterpret_cast<float4*>(&Xs[r8][seg]) =
          *reinterpret_cast<const float4*>(&input[(size_t)rows[r8] * 64 + seg]);
    }
    __syncthreads();

    const int j0 = tid * 4;
    double dot[8][4];
    double nrm[4];
#pragma unroll
    for (int r = 0; r < 8; ++r)
#pragma unroll
      for (int cc = 0; cc < 4; ++cc) dot[r][cc] = 0.0;
#pragma unroll
    for (int cc = 0; cc < 4; ++cc) nrm[cc] = 0.0;

    for (int d = 0; d < 64; ++d) {
      float4 e4 = *reinterpret_cast<const float4*>(&embed[d * NE + j0]);
      double ev[4] = {(double)e4.x, (double)e4.y, (double)e4.z, (double)e4.w};
#pragma unroll
      for (int cc = 0; cc < 4; ++cc) nrm[cc] = fma(ev[cc], ev[cc], nrm[cc]);
#pragma unroll
      for (int r = 0; r < 8; ++r) {
        double xr = (double)Xs[r][d];
#pragma unroll
        for (int cc = 0; cc < 4; ++cc) dot[r][cc] = fma(xr, ev[cc], dot[r][cc]);
      }
    }

#pragma unroll
    for (int r = 0; r < 8; ++r) {
      double bv = -1e300;
      int bi = 0;
#pragma unroll
      for (int cc = 0; cc < 4; ++cc) {
        double t = 2.0 * dot[r][cc] - nrm[cc];
        if (t > bv) {
          bv = t;
          bi = j0 + cc;
        }
      }
#pragma unroll
      for (int off = 1; off <= 32; off <<= 1) {
        double ob = __shfl_xor(bv, off);
        int oi = __shfl_xor(bi, off);
        if (ob > bv || (ob == bv && oi < bi)) {
          bv = ob;
          bi = oi;
        }
      }
      if (lane == 0) {
        Wv[wv][r] = bv;
        Wi[wv][r] = bi;
      }
    }
    __syncthreads();
    if (tid < 8) {
      double bv = Wv[0][tid];
      int bi = Wi[0][tid];
#pragma unroll
      for (int w = 1; w < 4; ++w) {
        double ob = Wv[w][tid];
        int oi = Wi[w][tid];
        if (ob > bv || (ob == bv && oi < bi)) {
          bv = ob;
          bi = oi;
        }
      }
      out[NELEM + rows[tid]] = (float)bi;
    }
  }
}

// ---------------- gather: out0 = hard codes; loss = sum (h-x)^2
__global__ void gather_kernel(const float* __restrict__ input, const float* __restrict__ et,
                              float* __restrict__ out, double* __restrict__ acc) {
  __shared__ double wred[4];
  const int tid = threadIdx.x;
  const size_t row = (size_t)blockIdx.x * 16 + (tid >> 4);
  const int seg = (tid & 15) * 4;
  const int idx = (int)out[NELEM + row];
  float4 h = *reinterpret_cast<const float4*>(&et[(size_t)idx * 64 + seg]);
  float4 x = *reinterpret_cast<const float4*>(&input[row * 64 + seg]);
  *reinterpret_cast<float4*>(&out[row * 64 + seg]) = h;
  float d0 = h.x - x.x, d1 = h.y - x.y, d2 = h.z - x.z, d3 = h.w - x.w;
  double pd = (double)(d0 * d0 + d1 * d1 + d2 * d2 + d3 * d3);
#pragma unroll
  for (int off = 1; off <= 32; off <<= 1) pd += __shfl_xor(pd, off);
  if ((tid & 63) == 0) wred[tid >> 6] = pd;
  __syncthreads();
  if (tid == 0) unsafeAtomicAdd(acc, wred[0] + wred[1] + wred[2] + wred[3]);
}

__global__ void finalize_kernel(const double* __restrict__ acc, float* __restrict__ out) {
  if (threadIdx.x == 0) {
    float v = (float)(acc[0] / (double)NELEM);
    out[NELEM + NROW + 0] = v;  // diff
    out[NELEM + NROW + 1] = v;  // embed_loss (== diff to ~1e-6 rel)
  }
}

extern "C" void kernel_launch(void* const* d_in, const int* in_sizes, int n_in,
                              void* d_out, int out_size, void* d_ws, size_t ws_size,
                              hipStream_t stream) {
  const float* input = (const float*)d_in[0];
  const float* embed = (const float*)d_in[1];
  float* out = (float*)d_out;
  char* ws = (char*)d_ws;
  ushort_t* bp = (ushort_t*)(ws + OFF_BPACK);
  float* cn = (float*)(ws + OFF_CN);
  float* et = (float*)(ws + OFF_ET);
  double* acc = (double*)(ws + OFF_ACC);
  int* fcnt = (int*)(ws + OFF_FCNT);
  int* flags = (int*)(ws + OFF_FLAGS);

  hipMemsetAsync(ws + OFF_ACC, 0, 12, stream);  // acc + fcnt
  prepack_kernel<<<4, 256, 0, stream>>>(embed, bp, cn, et);
  score_kernel<<<NROW / 128, 256, 0, stream>>>(input, bp, cn, out, fcnt, flags);
  fixup_kernel<<<256, 256, 0, stream>>>(input, embed, out, fcnt, flags);
  gather_kernel<<<NROW / 16, 256, 0, stream>>>(input, et, out, acc);
  finalize_kernel<<<1, 64, 0, stream>>>(acc, out);
}

// Round 5
// 174.603 us; speedup vs baseline: 2.4089x; 1.2620x over previous
//
#include <hip/hip_runtime.h>
#include <math.h>

typedef __attribute__((ext_vector_type(8))) short short8;
typedef __attribute__((ext_vector_type(4))) float f32x4;
typedef unsigned short ushort_t;
typedef unsigned int uint_t;

#define DIM 64
#define NE 1024
#define NROW 65536
#define NELEM (NROW * DIM)  // 4194304
#define MARGIN 0.1f

// ws layout (bytes):
#define OFF_BPACK 0        // 256 KB: bf16-split embed, MFMA B-frag order
#define OFF_CN 262144      // 4 KB: ||e_j||^2 fp32
#define OFF_ET 266240      // 256 KB: embed^T fp32 [code][d]
#define OFF_ACC 528384     // 8 B: f64 loss accumulator
#define OFF_FCNT 528392    // 4 B: flag count
#define OFF_FLAGS 528396   // 256 KB: flagged row ids

__device__ __forceinline__ ushort_t f2bf(float f) {
  uint_t u = __float_as_uint(f);
  uint_t r = (u + 0x7FFFu + ((u >> 16) & 1u)) >> 16;
  return (ushort_t)r;
}

// ---------------- prepack: embed -> {B-frag bf16 hi/lo, colnorms, embed^T}
// 32 blocks x 256 threads; block handles 32 codes, thread handles 8 dims of one code.
__global__ void prepack_kernel(const float* __restrict__ embed, ushort_t* __restrict__ bp,
                               float* __restrict__ cn, float* __restrict__ et) {
  __shared__ float nsum[8][32];
  const int tid = threadIdx.x;
  const int cl_ = tid & 31;   // code within block
  const int dg = tid >> 5;    // 0..7 dim group
  const int code = blockIdx.x * 32 + cl_;
  const int c16 = code >> 4, cl = code & 15;

  float vals[8];
  float nrm = 0.f;
#pragma unroll
  for (int jd = 0; jd < 8; ++jd) {
    int d = dg * 8 + jd;
    float e = embed[d * NE + code];
    vals[jd] = e;
    nrm = fmaf(e, e, nrm);
  }
  nsum[dg][cl_] = nrm;

  float4 a = {vals[0], vals[1], vals[2], vals[3]};
  float4 b4 = {vals[4], vals[5], vals[6], vals[7]};
  *reinterpret_cast<float4*>(&et[(size_t)code * 64 + dg * 8]) = a;
  *reinterpret_cast<float4*>(&et[(size_t)code * 64 + dg * 8 + 4]) = b4;

#pragma unroll
  for (int jd = 0; jd < 8; ++jd) {
    int d = dg * 8 + jd;
    ushort_t h = f2bf(vals[jd]);
    float hf = __uint_as_float((uint_t)h << 16);
    ushort_t lo = f2bf(vals[jd] - hf);
    int lane = cl + ((d >> 3) & 3) * 16;
    int j = d & 7;
    int kk = d >> 5;
    bp[(((c16 * 4) + kk) * 64 + lane) * 8 + j] = h;       // hi sections 0,1
    bp[(((c16 * 4) + 2 + kk) * 64 + lane) * 8 + j] = lo;  // lo sections 2,3
  }
  __syncthreads();
  if (tid < 32) {
    float s = 0.f;
#pragma unroll
    for (int w = 0; w < 8; ++w) s += nsum[w][tid];
    cn[blockIdx.x * 32 + tid] = s;
  }
}

// ---------------- score: split-bf16 MFMA, counted-vmcnt pipeline, fused gather epilogue
__launch_bounds__(256, 2)
__global__ void score_kernel(const float* __restrict__ input, const ushort_t* __restrict__ bp,
                             const float* __restrict__ cn, const float* __restrict__ et,
                             float* __restrict__ out, double* __restrict__ acc,
                             int* __restrict__ fcnt, int* __restrict__ flags) {
  __shared__ short8 Bs[3][4][64];  // 3-deep: [buf][sec: hi_k0,hi_k1,lo_k0,lo_k1][lane]
  __shared__ float cns[NE];
  __shared__ double wredd[4];

  const int tid = threadIdx.x;
  const int wave = tid >> 6, lane = tid & 63;
  const int col = lane & 15, g = lane >> 4;
  const long rowbase = (long)blockIdx.x * 128 + wave * 32;  // 2 row-tiles of 16 per wave

  // stage colnorms to LDS
  *reinterpret_cast<float4*>(&cns[tid * 4]) = *reinterpret_cast<const float4*>(&cn[tid * 4]);

#define STAGE(b, c)                                                                            \
  __builtin_amdgcn_global_load_lds(                                                           \
      (const __attribute__((address_space(1))) void*)((const char*)bp + (c) * 4096 + tid * 16), \
      (__attribute__((address_space(3))) void*)((char*)&Bs[0][0][0] + (b) * 4096 + wave * 1024), \
      16, 0, 0)

  STAGE(0, 0);
  STAGE(1, 1);

  // A fragments: X rows in bf16 hi/lo, resident all-kernel
  short8 ah[2][2], al[2][2];
#pragma unroll
  for (int rt = 0; rt < 2; ++rt)
#pragma unroll
    for (int kk = 0; kk < 2; ++kk) {
      const float* xp = &input[(size_t)(rowbase + rt * 16 + col) * 64 + kk * 32 + g * 8];
      float4 x0 = *reinterpret_cast<const float4*>(xp);
      float4 x1 = *reinterpret_cast<const float4*>(xp + 4);
      float xs[8] = {x0.x, x0.y, x0.z, x0.w, x1.x, x1.y, x1.z, x1.w};
#pragma unroll
      for (int j = 0; j < 8; ++j) {
        ushort_t h = f2bf(xs[j]);
        ah[rt][kk][j] = (short)h;
        float hf = __uint_as_float((uint_t)h << 16);
        al[rt][kk][j] = (short)f2bf(xs[j] - hf);
      }
    }

  float v1[2][4], v2[2][4];
  int i1[2][4];
#pragma unroll
  for (int rt = 0; rt < 2; ++rt)
#pragma unroll
    for (int r = 0; r < 4; ++r) {
      v1[rt][r] = -INFINITY;
      v2[rt][r] = -INFINITY;
      i1[rt][r] = 0;
    }

  __syncthreads();  // full drain once: cns + A-frags + chunks 0,1 staged

  int buf = 0, sbuf = 2;
#pragma unroll 1
  for (int c = 0; c < 64; ++c) {
    // own stage(c) landed (steady state: outstanding {c, c+1} -> retire c)
    if (c < 63) {
      asm volatile("s_waitcnt vmcnt(1)" ::: "memory");
    } else {
      asm volatile("s_waitcnt vmcnt(0)" ::: "memory");
    }
    __builtin_amdgcn_s_barrier();  // all waves' quarters of chunk c visible; all done reading buf (c+2)%3
    __builtin_amdgcn_sched_barrier(0);
    if (c < 62) STAGE(sbuf, c + 2);

    short8 bh0 = Bs[buf][0][lane];
    short8 bh1 = Bs[buf][1][lane];
    short8 bl0 = Bs[buf][2][lane];
    short8 bl1 = Bs[buf][3][lane];
    float cnv = cns[c * 16 + col];

    f32x4 accA = {0.f, 0.f, 0.f, 0.f};
    f32x4 accB = {0.f, 0.f, 0.f, 0.f};
    accA = __builtin_amdgcn_mfma_f32_16x16x32_bf16(ah[0][0], bh0, accA, 0, 0, 0);
    accB = __builtin_amdgcn_mfma_f32_16x16x32_bf16(ah[1][0], bh0, accB, 0, 0, 0);
    accA = __builtin_amdgcn_mfma_f32_16x16x32_bf16(ah[0][1], bh1, accA, 0, 0, 0);
    accB = __builtin_amdgcn_mfma_f32_16x16x32_bf16(ah[1][1], bh1, accB, 0, 0, 0);
    accA = __builtin_amdgcn_mfma_f32_16x16x32_bf16(al[0][0], bh0, accA, 0, 0, 0);
    accB = __builtin_amdgcn_mfma_f32_16x16x32_bf16(al[1][0], bh0, accB, 0, 0, 0);
    accA = __builtin_amdgcn_mfma_f32_16x16x32_bf16(al[0][1], bh1, accA, 0, 0, 0);
    accB = __builtin_amdgcn_mfma_f32_16x16x32_bf16(al[1][1], bh1, accB, 0, 0, 0);
    accA = __builtin_amdgcn_mfma_f32_16x16x32_bf16(ah[0][0], bl0, accA, 0, 0, 0);
    accB = __builtin_amdgcn_mfma_f32_16x16x32_bf16(ah[1][0], bl0, accB, 0, 0, 0);
    accA = __builtin_amdgcn_mfma_f32_16x16x32_bf16(ah[0][1], bl1, accA, 0, 0, 0);
    accB = __builtin_amdgcn_mfma_f32_16x16x32_bf16(ah[1][1], bl1, accB, 0, 0, 0);

    const int code = c * 16 + col;
#pragma unroll
    for (int r = 0; r < 4; ++r) {
      float v = fmaf(2.f, accA[r], -cnv);
      float nv2 = fmaxf(v2[0][r], fminf(v1[0][r], v));
      bool gt = v > v1[0][r];
      i1[0][r] = gt ? code : i1[0][r];
      v1[0][r] = gt ? v : v1[0][r];
      v2[0][r] = nv2;
    }
#pragma unroll
    for (int r = 0; r < 4; ++r) {
      float v = fmaf(2.f, accB[r], -cnv);
      float nv2 = fmaxf(v2[1][r], fminf(v1[1][r], v));
      bool gt = v > v1[1][r];
      i1[1][r] = gt ? code : i1[1][r];
      v1[1][r] = gt ? v : v1[1][r];
      v2[1][r] = nv2;
    }
    buf = (buf == 2) ? 0 : buf + 1;
    sbuf = (sbuf == 2) ? 0 : sbuf + 1;
  }
#undef STAGE

  // epilogue: merge top-2 across 16 col-lanes; gather hard codes; write out0+idx; loss
  double lsum = 0.0;
#pragma unroll
  for (int rt = 0; rt < 2; ++rt)
#pragma unroll
    for (int r = 0; r < 4; ++r) {
      float bv1 = v1[rt][r], bv2 = v2[rt][r];
      int bidx = i1[rt][r];
#pragma unroll
      for (int off = 1; off <= 8; off <<= 1) {
        float ov1 = __shfl_xor(bv1, off);
        int oi = __shfl_xor(bidx, off);
        float ov2 = __shfl_xor(bv2, off);
        bool take = (ov1 > bv1) || (ov1 == bv1 && oi < bidx);
        float nv2 = take ? fmaxf(bv1, ov2) : fmaxf(bv2, ov1);
        bv1 = take ? ov1 : bv1;
        bidx = take ? oi : bidx;
        bv2 = nv2;
      }
      long row = rowbase + rt * 16 + g * 4 + r;
      float4 h = *reinterpret_cast<const float4*>(&et[(size_t)bidx * 64 + col * 4]);
      float4 x = *reinterpret_cast<const float4*>(&input[(size_t)row * 64 + col * 4]);
      *reinterpret_cast<float4*>(&out[(size_t)row * 64 + col * 4]) = h;
      float d0 = h.x - x.x, d1 = h.y - x.y, d2 = h.z - x.z, d3 = h.w - x.w;
      lsum += (double)(d0 * d0 + d1 * d1 + d2 * d2 + d3 * d3);
      if (col == 0) {
        out[NELEM + row] = (float)bidx;
        if (bv1 - bv2 < MARGIN) {
          int p = atomicAdd(fcnt, 1);
          flags[p] = (int)row;
        }
      }
    }

#pragma unroll
  for (int off = 1; off <= 32; off <<= 1) lsum += __shfl_xor(lsum, off);
  if (lane == 0) wredd[wave] = lsum;
  __syncthreads();
  if (tid == 0) unsafeAtomicAdd(acc, wredd[0] + wredd[1] + wredd[2] + wredd[3]);
}

// ---------------- fixup: exact f64 argmax for flagged rows; repair idx, out0, loss
__global__ void fixup_kernel(const float* __restrict__ input, const float* __restrict__ embed,
                             const float* __restrict__ et, float* __restrict__ out,
                             double* __restrict__ acc, const int* __restrict__ fcnt,
                             const int* __restrict__ flags) {
  __shared__ float Xs[8][64];
  __shared__ double Wv[4][8];
  __shared__ int Wi[4][8];
  __shared__ int NewI[8], OldI[8], Rw[8];
  const int tid = threadIdx.x;
  const int lane = tid & 63, wv = tid >> 6;
  const int count = *fcnt;

  for (int base = blockIdx.x * 8; base < count; base += 256 * 8) {
    __syncthreads();  // previous pass done with shared
    if (tid < 8) {
      int p = base + tid;
      int r = (p < count) ? flags[p] : flags[count - 1];
      Rw[tid] = r;
      OldI[tid] = (int)out[NELEM + r];
    }
    __syncthreads();
    if (tid < 128) {
      int r8 = tid >> 4, seg = (tid & 15) * 4;
      *reinterpret_cast<float4*>(&Xs[r8][seg]) =
          *reinterpret_cast<const float4*>(&input[(size_t)Rw[r8] * 64 + seg]);
    }
    __syncthreads();

    const int j0 = tid * 4;
    double dot[8][4];
    double nrm[4];
#pragma unroll
    for (int r = 0; r < 8; ++r)
#pragma unroll
      for (int cc = 0; cc < 4; ++cc) dot[r][cc] = 0.0;
#pragma unroll
    for (int cc = 0; cc < 4; ++cc) nrm[cc] = 0.0;

    for (int d = 0; d < 64; ++d) {
      float4 e4 = *reinterpret_cast<const float4*>(&embed[d * NE + j0]);
      double ev[4] = {(double)e4.x, (double)e4.y, (double)e4.z, (double)e4.w};
#pragma unroll
      for (int cc = 0; cc < 4; ++cc) nrm[cc] = fma(ev[cc], ev[cc], nrm[cc]);
#pragma unroll
      for (int r = 0; r < 8; ++r) {
        double xr = (double)Xs[r][d];
#pragma unroll
        for (int cc = 0; cc < 4; ++cc) dot[r][cc] = fma(xr, ev[cc], dot[r][cc]);
      }
    }

#pragma unroll
    for (int r = 0; r < 8; ++r) {
      double bv = -1e300;
      int bi = 0;
#pragma unroll
      for (int cc = 0; cc < 4; ++cc) {
        double t = 2.0 * dot[r][cc] - nrm[cc];
        if (t > bv) {
          bv = t;
          bi = j0 + cc;
        }
      }
#pragma unroll
      for (int off = 1; off <= 32; off <<= 1) {
        double ob = __shfl_xor(bv, off);
        int oi = __shfl_xor(bi, off);
        if (ob > bv || (ob == bv && oi < bi)) {
          bv = ob;
          bi = oi;
        }
      }
      if (lane == 0) {
        Wv[wv][r] = bv;
        Wi[wv][r] = bi;
      }
    }
    __syncthreads();
    if (tid < 8) {
      double bv = Wv[0][tid];
      int bi = Wi[0][tid];
#pragma unroll
      for (int w = 1; w < 4; ++w) {
        double ob = Wv[w][tid];
        int oi = Wi[w][tid];
        if (ob > bv || (ob == bv && oi < bi)) {
          bv = ob;
          bi = oi;
        }
      }
      NewI[tid] = bi;
      if (base + tid < count && bi != OldI[tid]) out[NELEM + Rw[tid]] = (float)bi;
    }
    __syncthreads();
    if (tid < 128) {
      int r8 = tid >> 4, seg = (tid & 15) * 4;
      if (base + r8 < count && NewI[r8] != OldI[r8]) {
        float4 hn = *reinterpret_cast<const float4*>(&et[(size_t)NewI[r8] * 64 + seg]);
        float4 ho = *reinterpret_cast<const float4*>(&et[(size_t)OldI[r8] * 64 + seg]);
        float4 x = *reinterpret_cast<const float4*>(&Xs[r8][seg]);
        *reinterpret_cast<float4*>(&out[(size_t)Rw[r8] * 64 + seg]) = hn;
        float n0 = hn.x - x.x, n1 = hn.y - x.y, n2 = hn.z - x.z, n3 = hn.w - x.w;
        float o0 = ho.x - x.x, o1 = ho.y - x.y, o2 = ho.z - x.z, o3 = ho.w - x.w;
        double delta = (double)(n0 * n0 + n1 * n1 + n2 * n2 + n3 * n3) -
                       (double)(o0 * o0 + o1 * o1 + o2 * o2 + o3 * o3);
        unsafeAtomicAdd(acc, delta);
      }
    }
  }
}

__global__ void finalize_kernel(const double* __restrict__ acc, float* __restrict__ out) {
  if (threadIdx.x == 0) {
    float v = (float)(acc[0] / (double)NELEM);
    out[NELEM + NROW + 0] = v;  // diff
    out[NELEM + NROW + 1] = v;  // embed_loss (== diff to ~1e-7 rel)
  }
}

extern "C" void kernel_launch(void* const* d_in, const int* in_sizes, int n_in,
                              void* d_out, int out_size, void* d_ws, size_t ws_size,
                              hipStream_t stream) {
  const float* input = (const float*)d_in[0];
  const float* embed = (const float*)d_in[1];
  float* out = (float*)d_out;
  char* ws = (char*)d_ws;
  ushort_t* bp = (ushort_t*)(ws + OFF_BPACK);
  float* cn = (float*)(ws + OFF_CN);
  float* et = (float*)(ws + OFF_ET);
  double* acc = (double*)(ws + OFF_ACC);
  int* fcnt = (int*)(ws + OFF_FCNT);
  int* flags = (int*)(ws + OFF_FLAGS);

  hipMemsetAsync(ws + OFF_ACC, 0, 12, stream);  // acc + fcnt
  prepack_kernel<<<32, 256, 0, stream>>>(embed, bp, cn, et);
  score_kernel<<<NROW / 128, 256, 0, stream>>>(input, bp, cn, et, out, acc, fcnt, flags);
  fixup_kernel<<<256, 256, 0, stream>>>(input, embed, et, out, acc, fcnt, flags);
  finalize_kernel<<<1, 64, 0, stream>>>(acc, out);
}